// Round 2
// baseline (89.354 us; speedup 1.0000x reference)
//
#include <hip/hip_runtime.h>

// L1 pairwise distance: out[i][j] = sum_d |x1[i][d] - x2[j][d]|
// x1: [2048, 64] f32, x2: [2048, 64] f32, out: [2048, 2048] f32.
// Mean-adjustment in the reference cancels: (x1-adj)-(x2-adj) = x1-x2.
// clamp_min(0) is a no-op on a sum of |.|.
//
// Structure (R1): LDS-free. Lane owns column j (x2[j][*] in 64 VGPRs);
// x1[i][d] is wave-uniform -> scalar s_load_dwordx4, feeds v_sub_f32 src0.
// Inner loop = 2 VALU per (d, output): v_sub_f32 + v_add_f32 w/ abs modifier.

#define D_FIXED 64
#define ROWS 16   // output rows per thread; x2 refetch = (2048/ROWS)*512KB = 67MB (L2)

__global__ __launch_bounds__(256, 4)
void l1dist_kernel(const float* __restrict__ x1, const float* __restrict__ x2,
                   float* __restrict__ out, int N1, int N2) {
    const int j  = blockIdx.x * 256 + threadIdx.x;  // output column (lane-varying)
    const int i0 = blockIdx.y * ROWS;               // first output row (uniform)

    // ---- x2 column j -> 64 VGPRs (16x global_load_dwordx4, one-time) ----
    float v[D_FIXED];
    const float* p2 = x2 + (size_t)j * D_FIXED;
    #pragma unroll
    for (int d = 0; d < D_FIXED; d += 4) {
        float4 q = *(const float4*)(p2 + d);
        v[d + 0] = q.x; v[d + 1] = q.y; v[d + 2] = q.z; v[d + 3] = q.w;
    }

    // ---- per row: 64x (scalar-broadcast sub + abs-add); 4 partial accs for ILP ----
    #pragma unroll 2
    for (int r = 0; r < ROWS; ++r) {
        const int i = i0 + r;
        const float* p1 = x1 + (size_t)i * D_FIXED;  // uniform -> scalar loads
        float a0 = 0.f, a1 = 0.f, a2 = 0.f, a3 = 0.f;
        #pragma unroll
        for (int d = 0; d < D_FIXED; d += 4) {
            float4 q = *(const float4*)(p1 + d);     // s_load_dwordx4 (uniform)
            a0 += fabsf(q.x - v[d + 0]);
            a1 += fabsf(q.y - v[d + 1]);
            a2 += fabsf(q.z - v[d + 2]);
            a3 += fabsf(q.w - v[d + 3]);
        }
        out[(size_t)i * N2 + j] = (a0 + a1) + (a2 + a3);  // coalesced 256B/wave
    }
}

extern "C" void kernel_launch(void* const* d_in, const int* in_sizes, int n_in,
                              void* d_out, int out_size, void* d_ws, size_t ws_size,
                              hipStream_t stream) {
    const float* x1 = (const float*)d_in[0];
    const float* x2 = (const float*)d_in[1];
    float* out = (float*)d_out;

    const int N1 = in_sizes[0] / D_FIXED;  // 2048
    const int N2 = in_sizes[1] / D_FIXED;  // 2048

    dim3 block(256);
    dim3 grid(N2 / 256, N1 / ROWS);        // (8, 128) = 1024 blocks, 4/CU
    l1dist_kernel<<<grid, block, 0, stream>>>(x1, x2, out, N1, N2);
}

// Round 3
// 70.866 us; speedup vs baseline: 1.2609x; 1.2609x over previous
//
#include <hip/hip_runtime.h>

// L1 pairwise distance: out[i][j] = sum_d |x1[i][d] - x2[j][d]|
// x1: [2048, 64] f32, x2: [2048, 64] f32, out: [2048, 2048] f32.
// Mean-adjustment in the reference cancels: (x1-adj)-(x2-adj) = x1-x2.
// clamp_min(0) is a no-op on a sum of |.|.
//
// R2 structure: D=64 is the whole depth -> stage both tiles to LDS ONCE,
// one barrier, then pure register compute. 128x64 tile / block, 8x4 per
// thread: LDS traffic 402MB (~5.8us) < VALU pole 6.8us (536M lane-ops).
// 512 blocks = 2/CU, 2 waves/SIMD. ~110 VGPR, no spill (R1's failure mode).

#define D_FIXED 64
#define BI 128   // x1 rows per block
#define BJ 64    // x2 cols per block
#define PAD 68   // 68 floats = 272B: 16B-aligned rows, bank shift 4/row -> <=2-way (free)

__global__ __launch_bounds__(256, 2)
void l1dist_kernel(const float* __restrict__ x1, const float* __restrict__ x2,
                   float* __restrict__ out, int N1, int N2) {
    __shared__ float s1[BI * PAD];  // 34816 B
    __shared__ float s2[BJ * PAD];  // 17408 B  (total ~51KB -> 2-3 blocks/CU)

    const int tx = threadIdx.x;     // 0..15
    const int ty = threadIdx.y;     // 0..15
    const int t  = ty * 16 + tx;
    const int i0 = blockIdx.y * BI;
    const int j0 = blockIdx.x * BJ;

    // ---- one-shot staging (coalesced float4) ----
    const float* g1 = x1 + (size_t)i0 * D_FIXED;
    #pragma unroll
    for (int f = 0; f < 8; ++f) {           // 2048 float4s / 256 threads
        int idx = t + f * 256;
        int row = idx >> 4;
        int c4  = (idx & 15) << 2;
        *(float4*)(s1 + row * PAD + c4) = *(const float4*)(g1 + row * D_FIXED + c4);
    }
    const float* g2 = x2 + (size_t)j0 * D_FIXED;
    #pragma unroll
    for (int f = 0; f < 4; ++f) {           // 1024 float4s / 256 threads
        int idx = t + f * 256;
        int row = idx >> 4;
        int c4  = (idx & 15) << 2;
        *(float4*)(s2 + row * PAD + c4) = *(const float4*)(g2 + row * D_FIXED + c4);
    }
    __syncthreads();                         // the ONLY barrier

    // ---- 8x4 register tile: rows i = ty+16r, cols j = tx+16c ----
    float acc[8][4];
    #pragma unroll
    for (int r = 0; r < 8; ++r)
        #pragma unroll
        for (int c = 0; c < 4; ++c) acc[r][c] = 0.0f;

    #pragma unroll
    for (int d = 0; d < D_FIXED; d += 4) {
        float4 a[8], b[4];
        #pragma unroll
        for (int r = 0; r < 8; ++r)          // wave-broadcast (4 addrs/wave)
            a[r] = *(const float4*)(s1 + (ty + 16 * r) * PAD + d);
        #pragma unroll
        for (int c = 0; c < 4; ++c)          // <=2-way bank alias (free)
            b[c] = *(const float4*)(s2 + (tx + 16 * c) * PAD + d);

        #pragma unroll
        for (int r = 0; r < 8; ++r) {
            #pragma unroll
            for (int c = 0; c < 4; ++c) {
                float d0 = a[r].x - b[c].x;
                float d1 = a[r].y - b[c].y;
                float d2 = a[r].z - b[c].z;
                float d3 = a[r].w - b[c].w;
                // abs folds into v_add_f32 input modifiers: 4 sub + 4 add per 4 elems
                acc[r][c] += (fabsf(d0) + fabsf(d1)) + (fabsf(d2) + fabsf(d3));
            }
        }
    }

    // ---- store: per (r,c) a wave covers 4 rows x 64B segments ----
    #pragma unroll
    for (int r = 0; r < 8; ++r) {
        const size_t i = i0 + ty + 16 * r;
        #pragma unroll
        for (int c = 0; c < 4; ++c) {
            const int j = j0 + tx + 16 * c;
            out[i * N2 + j] = acc[r][c];
        }
    }
}

extern "C" void kernel_launch(void* const* d_in, const int* in_sizes, int n_in,
                              void* d_out, int out_size, void* d_ws, size_t ws_size,
                              hipStream_t stream) {
    const float* x1 = (const float*)d_in[0];
    const float* x2 = (const float*)d_in[1];
    float* out = (float*)d_out;

    const int N1 = in_sizes[0] / D_FIXED;  // 2048
    const int N2 = in_sizes[1] / D_FIXED;  // 2048

    dim3 block(16, 16);
    dim3 grid(N2 / BJ, N1 / BI);           // (32, 16) = 512 blocks = 2/CU
    l1dist_kernel<<<grid, block, 0, stream>>>(x1, x2, out, N1, N2);
}